// Round 9
// baseline (129.956 us; speedup 1.0000x reference)
//
#include <hip/hip_runtime.h>
#include <math.h>

#define BB 4
#define NN 4096
#define MM 512
#define MH (MM / 2)            // triangles per block (split-m)
#define PTS 8                  // point-slots per block
#define NPT 4                  // points per thread = 2 packed float2 groups
#define MCHUNK (MH / 64)       // 4 triangles per chunk (64 chunks, one per ch)
#define TPB 512
#define NPTS_TOT (BB * NN)     // 16384 points

typedef float v2 __attribute__((ext_vector_type(2)));

__device__ __forceinline__ v2 pfma(v2 a, v2 b, v2 c) {
    return __builtin_elementwise_fma(a, b, c);
}
__device__ __forceinline__ v2 pmin(v2 a, v2 b) { return __builtin_elementwise_min(a, b); }
__device__ __forceinline__ v2 pmax(v2 a, v2 b) { return __builtin_elementwise_max(a, b); }
__device__ __forceinline__ v2 pclip01(v2 x) { return pmin(pmax(x, (v2)0.0f), (v2)1.0f); }

// reference _safe_div guard + hw rcp (~1 ulp) -- relative-class error, argmin-safe (R4-R8 validated)
__device__ __forceinline__ float safercp(float y) {
    float yy = (fabsf(y) < 1e-12f) ? 1.0f : y;
    return __builtin_amdgcn_rcpf(yy);
}

// exact IEEE version for phase-2 (matches reference bit-order, validated R1/R3/R6-R8)
__device__ __forceinline__ float safediv(float x, float y) {
    float yy = (fabsf(y) < 1e-12f) ? 1.0f : y;
    return x / yy;
}

__device__ __forceinline__ float clip01s(float x) {
    return fminf(fmaxf(x, 0.0f), 1.0f);
}

// Phase 2: exact reference-ordered Ericson for ONE pair (R1-validated numerics).
__device__ void exact_pair(float px, float py, float pz,
                           float ax, float ay, float az,
                           float bx, float by, float bz,
                           float cx, float cy, float cz,
                           float* dist2_out, int* reg_out) {
#pragma clang fp contract(off)
    const float abx = bx-ax, aby = by-ay, abz = bz-az;
    const float acx = cx-ax, acy = cy-ay, acz = cz-az;
    const float cbx = cx-bx, cby = cy-by, cbz = cz-bz;
    const float apx = px-ax, apy = py-ay, apz = pz-az;
    const float bpx = px-bx, bpy = py-by, bpz = pz-bz;
    const float cpx = px-cx, cpy = py-cy, cpz = pz-cz;

    const float d1 = abx*apx + aby*apy + abz*apz;
    const float d2 = acx*apx + acy*apy + acz*apz;
    const float d3 = abx*bpx + aby*bpy + abz*bpz;
    const float d4 = acx*bpx + acy*bpy + acz*bpz;
    const float d5 = abx*cpx + aby*cpy + abz*cpz;
    const float d6 = acx*cpx + acy*cpy + acz*cpz;

    const float vc = d1*d4 - d3*d2;
    const float vb = d5*d2 - d1*d6;
    const float va = d3*d6 - d5*d4;

    const float v_ab = clip01s(safediv(d1, d1 - d3));
    const float v_ac = clip01s(safediv(d2, d2 - d6));
    const float t43 = d4 - d3;
    const float t56 = d5 - d6;
    const float v_bc = clip01s(safediv(t43, t43 + t56));
    const float denom = va + vb + vc;
    const float v_f = safediv(vb, denom);
    const float w_f = safediv(vc, denom);

    float qx = ax + v_f*abx + w_f*acx;
    float qy = ay + v_f*aby + w_f*acy;
    float qz = az + v_f*abz + w_f*acz;
    int reg = 6;
    const bool c_bc = (va <= 0.0f) && (t43 >= 0.0f) && (t56 >= 0.0f);
    if (c_bc) { qx = bx + v_bc*cbx; qy = by + v_bc*cby; qz = bz + v_bc*cbz; reg = 5; }
    const bool c_ac = (vb <= 0.0f) && (d2 >= 0.0f) && (d6 <= 0.0f);
    if (c_ac) { qx = ax + v_ac*acx; qy = ay + v_ac*acy; qz = az + v_ac*acz; reg = 4; }
    const bool c_c = (d6 >= 0.0f) && (d5 <= d6);
    if (c_c) { qx = cx; qy = cy; qz = cz; reg = 2; }
    const bool c_ab = (vc <= 0.0f) && (d1 >= 0.0f) && (d3 <= 0.0f);
    if (c_ab) { qx = ax + v_ab*abx; qy = ay + v_ab*aby; qz = az + v_ab*abz; reg = 3; }
    const bool c_b = (d3 >= 0.0f) && (d4 <= d3);
    if (c_b) { qx = bx; qy = by; qz = bz; reg = 1; }
    const bool c_a = (d1 <= 0.0f) && (d2 <= 0.0f);
    if (c_a) { qx = ax; qy = ay; qz = az; reg = 0; }

    const float dx = px - qx;
    const float dy = py - qy;
    const float dz = pz - qz;
    *dist2_out = dx*dx + dy*dy + dz*dz;
    *reg_out = reg;
}

// ---- phase-1 kernel: per-(point, m-half) best dist + argmin to d_ws ----
__global__ __launch_bounds__(TPB, 8) void tridist_p1(
    const float* __restrict__ xyz1, const float* __restrict__ tri1,
    const float* __restrict__ tri2, const float* __restrict__ tri3,
    float* __restrict__ wd, int* __restrict__ wj)
{
    // 6 float4 per record, groups of 8 records padded to 49 float4 ->
    // wave's 8 record groups start on banks {0,4,...,28}: conflict-free (R7/R8-validated).
    __shared__ float4 sT[(MH / 8) * 49];      // 25088 B
    __shared__ float  sPd[NPT][64];
    __shared__ int    sPj[NPT][64];           // total ~27 KiB -> 4 blocks/CU, 32 waves/CU

    const int t    = threadIdx.x;
    const int half = blockIdx.x & 1;
    const int bp   = blockIdx.x >> 1;
    const int b    = bp >> 7;                // 128 point-blocks per batch
    const int pb   = bp & 127;
    const int pt   = t & (PTS - 1);
    const int ch   = t >> 3;                 // chunk [0,64)
    const int jbase = half * MH;

    // ---- stage + per-triangle precompute (threads 0..MH-1) ----
    if (t < MH) {
        const int jj = t;                    // local record index
        const float* g1 = tri1 + ((size_t)b * MM + jbase + jj) * 3;
        const float* g2 = tri2 + ((size_t)b * MM + jbase + jj) * 3;
        const float* g3 = tri3 + ((size_t)b * MM + jbase + jj) * 3;
        const float ax = g1[0], ay = g1[1], az = g1[2];
        const float bx = g2[0], by = g2[1], bz = g2[2];
        const float cx = g3[0], cy = g3[1], cz = g3[2];
        const float abx = bx-ax, aby = by-ay, abz = bz-az;
        const float acx = cx-ax, acy = cy-ay, acz = cz-az;
        const float cbx = cx-bx, cby = cy-by, cbz = cz-bz;
        const float aba  = fmaf(abz, az, fmaf(aby, ay, abx*ax));
        const float aca  = fmaf(acz, az, fmaf(acy, ay, acx*ax));
        const float ab2  = fmaf(abz, abz, fmaf(aby, aby, abx*abx));   // == d1-d3
        const float ac2  = fmaf(acz, acz, fmaf(acy, acy, acx*acx));   // == d2-d6
        const float cb2  = fmaf(cbz, cbz, fmaf(cby, cby, cbx*cbx));
        const float abac = fmaf(abz, acz, fmaf(aby, acy, abx*acx));
        const float nrx = fmaf(aby, acz, -(abz*acy));
        const float nry = fmaf(abz, acx, -(abx*acz));
        const float nrz = fmaf(abx, acy, -(aby*acx));
        const float n2  = fmaf(nrz, nrz, fmaf(nry, nry, nrx*nrx));
        const float rn  = __builtin_amdgcn_rsqf(fmaxf(n2, 1e-30f));
        const float nx = nrx*rn, ny = nry*rn, nz = nrz*rn;
        const float nna = -fmaf(nz, az, fmaf(ny, ay, nx*ax));
        const int base = (jj >> 3) * 49 + (jj & 7) * 6;
        sT[base + 0] = make_float4(ax, ay, az, nna);
        sT[base + 1] = make_float4(abx, aby, abz, safercp(ab2));
        sT[base + 2] = make_float4(acx, acy, acz, safercp(ac2));
        sT[base + 3] = make_float4(cbx, cby, cbz, safercp(cb2));
        sT[base + 4] = make_float4(nx, ny, nz, abac);
        sT[base + 5] = make_float4(-aba, -aca, ab2, ac2);
    }
    __syncthreads();

    // ---- 4 points per thread, packed as 2 x float2 ----
    v2 Px[2], Py[2], Pz[2];
#pragma unroll
    for (int np = 0; np < NPT; ++np) {
        const int gi = b * NN + pb * 32 + np * PTS + pt;
        Px[np >> 1][np & 1] = xyz1[gi*3 + 0];
        Py[np >> 1][np & 1] = xyz1[gi*3 + 1];
        Pz[np >> 1][np & 1] = xyz1[gi*3 + 2];
    }

    float bestd[NPT] = {INFINITY, INFINITY, INFINITY, INFINITY};
    int   bestj[NPT] = {0, 0, 0, 0};         // GLOBAL j (jbase+local)

    for (int i = 0; i < MCHUNK; ++i) {
        const int lj = ch * MCHUNK + i;      // local record index
        const int base = (lj >> 3) * 49 + (lj & 7) * 6;
        const float4 r0 = sT[base + 0];
        const float4 r1 = sT[base + 1];
        const float4 r2 = sT[base + 2];
        const float4 r3 = sT[base + 3];
        const float4 r4 = sT[base + 4];
        const float4 r5 = sT[base + 5];
        const float ax = r0.x, ay = r0.y, az = r0.z, nna = r0.w;
        const float abx = r1.x, aby = r1.y, abz = r1.z, rab2 = r1.w;
        const float acx = r2.x, acy = r2.y, acz = r2.z, rac2 = r2.w;
        const float cbx = r3.x, cby = r3.y, cbz = r3.z, rcb2 = r3.w;
        const float nx = r4.x, ny = r4.y, nz = r4.z, abac = r4.w;
        const float naba = r5.x, naca = r5.y, ab2 = r5.z, ac2 = r5.w;

#pragma unroll
        for (int g = 0; g < 2; ++g) {
            const v2 X = Px[g], Y = Py[g], Z = Pz[g];

            const v2 d1 = pfma((v2)abz, Z, pfma((v2)aby, Y, pfma((v2)abx, X, (v2)naba)));
            const v2 d2 = pfma((v2)acz, Z, pfma((v2)acy, Y, pfma((v2)acx, X, (v2)naca)));
            const v2 h  = pfma((v2)nz,  Z, pfma((v2)ny,  Y, pfma((v2)nx,  X, (v2)nna)));
            const v2 d3 = d1 - (v2)ab2;
            const v2 d4 = d2 - (v2)abac;
            const v2 d5 = d1 - (v2)abac;
            const v2 d6 = d2 - (v2)ac2;

            const v2 vc = pfma(d1, d4, -(d3*d2));
            const v2 vb = pfma(d5, d2, -(d1*d6));
            const v2 va = pfma(d3, d6, -(d5*d4));
            const v2 t43 = d4 - d3;

            const v2 v_ab = pclip01(d1 * (v2)rab2);
            const v2 v_ac = pclip01(d2 * (v2)rac2);
            const v2 v_bc = pclip01(t43 * (v2)rcb2);

            const v2 apx = X - (v2)ax, apy = Y - (v2)ay, apz = Z - (v2)az;
            const v2 bpx = apx - (v2)abx, bpy = apy - (v2)aby, bpz = apz - (v2)abz;

            v2 ex = pfma(-v_ab, (v2)abx, apx);
            v2 ey = pfma(-v_ab, (v2)aby, apy);
            v2 ez = pfma(-v_ab, (v2)abz, apz);
            const v2 dAB = pfma(ez, ez, pfma(ey, ey, ex*ex));
            ex = pfma(-v_ac, (v2)acx, apx);
            ey = pfma(-v_ac, (v2)acy, apy);
            ez = pfma(-v_ac, (v2)acz, apz);
            const v2 dAC = pfma(ez, ez, pfma(ey, ey, ex*ex));
            ex = pfma(-v_bc, (v2)cbx, bpx);
            ey = pfma(-v_bc, (v2)cby, bpy);
            ez = pfma(-v_bc, (v2)cbz, bpz);
            const v2 dBC = pfma(ez, ez, pfma(ey, ey, ex*ex));
            const v2 dF = h * h;

            const v2 mv   = pmin(pmin(va, vb), vc);
            const v2 dseg = pmin(pmin(dAB, dAC), dBC);

#pragma unroll
            for (int c = 0; c < 2; ++c) {
                const float dist2 = (mv[c] >= 0.0f) ? dF[c] : dseg[c];
                const int np = g * 2 + c;
                if (dist2 < bestd[np]) { bestd[np] = dist2; bestj[np] = jbase + lj; }
            }
        }
    }

    // ---- in-wave butterfly over the 8 chunks this wave holds ----
#pragma unroll
    for (int np = 0; np < NPT; ++np) {
        for (int off = 8; off <= 32; off <<= 1) {
            const float od = __shfl_xor(bestd[np], off, 64);
            const int   oj = __shfl_xor(bestj[np], off, 64);
            if (od < bestd[np] || (od == bestd[np] && oj < bestj[np])) {
                bestd[np] = od; bestj[np] = oj;
            }
        }
    }
    const int lane = t & 63;
    const int w    = t >> 6;                 // wave [0,8)
    if (lane < PTS) {
#pragma unroll
        for (int np = 0; np < NPT; ++np) {
            sPd[np][w * PTS + lane] = bestd[np];
            sPj[np][w * PTS + lane] = bestj[np];
        }
    }
    __syncthreads();

    if (t < 32) {
        const int np = t >> 3;
        const int p  = t & 7;
        float bd = INFINITY; int bj = 0;
        for (int k = 0; k < 8; ++k) {        // waves ascend -> chunks ascend -> j ascends
            const float dk = sPd[np][k * PTS + p];
            const int   jk = sPj[np][k * PTS + p];
            if (dk < bd || (dk == bd && jk < bj)) { bd = dk; bj = jk; }
        }
        const int gidx = b * NN + pb * 32 + t;   // t == np*8 + p
        wd[half * NPTS_TOT + gidx] = bd;
        wj[half * NPTS_TOT + gidx] = bj;
    }
}

// ---- phase-2 kernel: merge halves, exact recompute, write outputs ----
__global__ __launch_bounds__(256) void tridist_p2(
    const float* __restrict__ xyz1, const float* __restrict__ tri1,
    const float* __restrict__ tri2, const float* __restrict__ tri3,
    const float* __restrict__ wd, const int* __restrict__ wj,
    float* __restrict__ out)
{
    const int gidx = blockIdx.x * 256 + threadIdx.x;   // [0, 16384)
    const float d0 = wd[gidx];
    const float d1 = wd[NPTS_TOT + gidx];
    const int   j0 = wj[gidx];
    const int   j1 = wj[NPTS_TOT + gidx];
    // half0's j are all < half1's j, so strict < gives np.argmin first-occurrence.
    const int bj = (d1 < d0) ? j1 : j0;

    const int b = gidx >> 12;                // 4096 points per batch
    const float* g1 = tri1 + ((size_t)b * MM + bj) * 3;
    const float* g2 = tri2 + ((size_t)b * MM + bj) * 3;
    const float* g3 = tri3 + ((size_t)b * MM + bj) * 3;
    float dist2; int reg;
    exact_pair(xyz1[gidx*3+0], xyz1[gidx*3+1], xyz1[gidx*3+2],
               g1[0], g1[1], g1[2],
               g2[0], g2[1], g2[2],
               g3[0], g3[1], g3[2],
               &dist2, &reg);
    out[gidx]               = dist2;
    out[NPTS_TOT + gidx]    = (float)reg;
    out[2*NPTS_TOT + gidx]  = (float)bj;
}

extern "C" void kernel_launch(void* const* d_in, const int* in_sizes, int n_in,
                              void* d_out, int out_size, void* d_ws, size_t ws_size,
                              hipStream_t stream) {
    const float* xyz1 = (const float*)d_in[0];
    const float* tri1 = (const float*)d_in[1];
    const float* tri2 = (const float*)d_in[2];
    const float* tri3 = (const float*)d_in[3];
    float* out = (float*)d_out;

    float* wd = (float*)d_ws;                        // 2 * 16384 floats
    int*   wj = (int*)((char*)d_ws + 2 * NPTS_TOT * sizeof(float));

    dim3 grid1(BB * (NN / 32) * 2);   // 1024 blocks -> 4 blocks/CU, 32 waves/CU
    tridist_p1<<<grid1, TPB, 0, stream>>>(xyz1, tri1, tri2, tri3, wd, wj);

    dim3 grid2(NPTS_TOT / 256);       // 64 blocks
    tridist_p2<<<grid2, 256, 0, stream>>>(xyz1, tri1, tri2, tri3, wd, wj, out);
}

// Round 10
// 73.067 us; speedup vs baseline: 1.7786x; 1.7786x over previous
//
#include <hip/hip_runtime.h>
#include <math.h>

#define BB 4
#define NN 4096
#define MM 512
#define MH (MM / 2)            // triangles per block (split-m)
#define PTS 16                 // point-slots per block
#define NPT 2                  // points per thread = 1 packed float2 group
#define CHUNKS 32              // m-chunks
#define MCHUNK (MH / CHUNKS)   // 8 triangles per chunk (restores proven bank map)
#define TPB 512
#define NPTS_TOT (BB * NN)     // 16384 points

typedef float v2 __attribute__((ext_vector_type(2)));

__device__ __forceinline__ v2 pfma(v2 a, v2 b, v2 c) {
    return __builtin_elementwise_fma(a, b, c);
}
__device__ __forceinline__ v2 pmin(v2 a, v2 b) { return __builtin_elementwise_min(a, b); }
__device__ __forceinline__ v2 pmax(v2 a, v2 b) { return __builtin_elementwise_max(a, b); }
__device__ __forceinline__ v2 pclip01(v2 x) { return pmin(pmax(x, (v2)0.0f), (v2)1.0f); }

// reference _safe_div guard + hw rcp (~1 ulp) -- relative-class error, argmin-safe (R4-R8 validated)
__device__ __forceinline__ float safercp(float y) {
    float yy = (fabsf(y) < 1e-12f) ? 1.0f : y;
    return __builtin_amdgcn_rcpf(yy);
}

// exact IEEE version for phase-2 (matches reference bit-order, validated R1/R3/R6-R8)
__device__ __forceinline__ float safediv(float x, float y) {
    float yy = (fabsf(y) < 1e-12f) ? 1.0f : y;
    return x / yy;
}

__device__ __forceinline__ float clip01s(float x) {
    return fminf(fmaxf(x, 0.0f), 1.0f);
}

// Phase 2: exact reference-ordered Ericson for ONE pair (R1-validated numerics).
__device__ void exact_pair(float px, float py, float pz,
                           float ax, float ay, float az,
                           float bx, float by, float bz,
                           float cx, float cy, float cz,
                           float* dist2_out, int* reg_out) {
#pragma clang fp contract(off)
    const float abx = bx-ax, aby = by-ay, abz = bz-az;
    const float acx = cx-ax, acy = cy-ay, acz = cz-az;
    const float cbx = cx-bx, cby = cy-by, cbz = cz-bz;
    const float apx = px-ax, apy = py-ay, apz = pz-az;
    const float bpx = px-bx, bpy = py-by, bpz = pz-bz;
    const float cpx = px-cx, cpy = py-cy, cpz = pz-cz;

    const float d1 = abx*apx + aby*apy + abz*apz;
    const float d2 = acx*apx + acy*apy + acz*apz;
    const float d3 = abx*bpx + aby*bpy + abz*bpz;
    const float d4 = acx*bpx + acy*bpy + acz*bpz;
    const float d5 = abx*cpx + aby*cpy + abz*cpz;
    const float d6 = acx*cpx + acy*cpy + acz*cpz;

    const float vc = d1*d4 - d3*d2;
    const float vb = d5*d2 - d1*d6;
    const float va = d3*d6 - d5*d4;

    const float v_ab = clip01s(safediv(d1, d1 - d3));
    const float v_ac = clip01s(safediv(d2, d2 - d6));
    const float t43 = d4 - d3;
    const float t56 = d5 - d6;
    const float v_bc = clip01s(safediv(t43, t43 + t56));
    const float denom = va + vb + vc;
    const float v_f = safediv(vb, denom);
    const float w_f = safediv(vc, denom);

    float qx = ax + v_f*abx + w_f*acx;
    float qy = ay + v_f*aby + w_f*acy;
    float qz = az + v_f*abz + w_f*acz;
    int reg = 6;
    const bool c_bc = (va <= 0.0f) && (t43 >= 0.0f) && (t56 >= 0.0f);
    if (c_bc) { qx = bx + v_bc*cbx; qy = by + v_bc*cby; qz = bz + v_bc*cbz; reg = 5; }
    const bool c_ac = (vb <= 0.0f) && (d2 >= 0.0f) && (d6 <= 0.0f);
    if (c_ac) { qx = ax + v_ac*acx; qy = ay + v_ac*acy; qz = az + v_ac*acz; reg = 4; }
    const bool c_c = (d6 >= 0.0f) && (d5 <= d6);
    if (c_c) { qx = cx; qy = cy; qz = cz; reg = 2; }
    const bool c_ab = (vc <= 0.0f) && (d1 >= 0.0f) && (d3 <= 0.0f);
    if (c_ab) { qx = ax + v_ab*abx; qy = ay + v_ab*aby; qz = az + v_ab*abz; reg = 3; }
    const bool c_b = (d3 >= 0.0f) && (d4 <= d3);
    if (c_b) { qx = bx; qy = by; qz = bz; reg = 1; }
    const bool c_a = (d1 <= 0.0f) && (d2 <= 0.0f);
    if (c_a) { qx = ax; qy = ay; qz = az; reg = 0; }

    const float dx = px - qx;
    const float dy = py - qy;
    const float dz = pz - qz;
    *dist2_out = dx*dx + dy*dy + dz*dz;
    *reg_out = reg;
}

// ---- phase-1 kernel: per-(point, m-half) best dist + argmin to d_ws ----
// launch_bounds min-waves=6 -> VGPR cap ~80: spill-proof; if actual VGPR <= 64,
// HW still grants 8 waves/EU (32 waves/CU). R9's (512,8) cap caused scratch spills.
__global__ __launch_bounds__(TPB, 6) void tridist_p1(
    const float* __restrict__ xyz1, const float* __restrict__ tri1,
    const float* __restrict__ tri2, const float* __restrict__ tri3,
    float* __restrict__ wd, int* __restrict__ wj)
{
    // 6 float4 per record, groups of 8 records padded to 49 float4.
    // Wave touches 4 records spaced 8 apart (lj = ch*8+i, ch = t>>4):
    // group bases 49*(4w+c) -> banks {0,4,8,12}, 16-lane broadcast each ->
    // conflict-free (R5/R6/R8-proven mapping; R9's MCHUNK=4 broke this).
    __shared__ float4 sT[(MH / 8) * 49];      // 25088 B
    __shared__ float  sPd[NPT][128];
    __shared__ int    sPj[NPT][128];          // total ~27 KiB

    const int t    = threadIdx.x;
    const int half = blockIdx.x & 1;
    const int bp   = blockIdx.x >> 1;
    const int b    = bp >> 7;                // 128 point-blocks per batch
    const int pb   = bp & 127;
    const int pt   = t & (PTS - 1);
    const int ch   = t >> 4;                 // chunk [0,32)
    const int jbase = half * MH;

    // ---- stage + per-triangle precompute (threads 0..MH-1) ----
    if (t < MH) {
        const int jj = t;                    // local record index
        const float* g1 = tri1 + ((size_t)b * MM + jbase + jj) * 3;
        const float* g2 = tri2 + ((size_t)b * MM + jbase + jj) * 3;
        const float* g3 = tri3 + ((size_t)b * MM + jbase + jj) * 3;
        const float ax = g1[0], ay = g1[1], az = g1[2];
        const float bx = g2[0], by = g2[1], bz = g2[2];
        const float cx = g3[0], cy = g3[1], cz = g3[2];
        const float abx = bx-ax, aby = by-ay, abz = bz-az;
        const float acx = cx-ax, acy = cy-ay, acz = cz-az;
        const float cbx = cx-bx, cby = cy-by, cbz = cz-bz;
        const float aba  = fmaf(abz, az, fmaf(aby, ay, abx*ax));
        const float aca  = fmaf(acz, az, fmaf(acy, ay, acx*ax));
        const float ab2  = fmaf(abz, abz, fmaf(aby, aby, abx*abx));   // == d1-d3
        const float ac2  = fmaf(acz, acz, fmaf(acy, acy, acx*acx));   // == d2-d6
        const float cb2  = fmaf(cbz, cbz, fmaf(cby, cby, cbx*cbx));
        const float abac = fmaf(abz, acz, fmaf(aby, acy, abx*acx));
        const float nrx = fmaf(aby, acz, -(abz*acy));
        const float nry = fmaf(abz, acx, -(abx*acz));
        const float nrz = fmaf(abx, acy, -(aby*acx));
        const float n2  = fmaf(nrz, nrz, fmaf(nry, nry, nrx*nrx));
        const float rn  = __builtin_amdgcn_rsqf(fmaxf(n2, 1e-30f));
        const float nx = nrx*rn, ny = nry*rn, nz = nrz*rn;
        const float nna = -fmaf(nz, az, fmaf(ny, ay, nx*ax));
        const int base = (jj >> 3) * 49 + (jj & 7) * 6;
        sT[base + 0] = make_float4(ax, ay, az, nna);
        sT[base + 1] = make_float4(abx, aby, abz, safercp(ab2));
        sT[base + 2] = make_float4(acx, acy, acz, safercp(ac2));
        sT[base + 3] = make_float4(cbx, cby, cbz, safercp(cb2));
        sT[base + 4] = make_float4(nx, ny, nz, abac);
        sT[base + 5] = make_float4(-aba, -aca, ab2, ac2);
    }
    __syncthreads();

    // ---- 2 points per thread, packed as 1 x float2 ----
    v2 X, Y, Z;
#pragma unroll
    for (int np = 0; np < NPT; ++np) {
        const int gi = b * NN + pb * 32 + np * PTS + pt;
        X[np] = xyz1[gi*3 + 0];
        Y[np] = xyz1[gi*3 + 1];
        Z[np] = xyz1[gi*3 + 2];
    }

    float bestd[NPT] = {INFINITY, INFINITY};
    int   bestj[NPT] = {0, 0};               // GLOBAL j (jbase+local)

    for (int i = 0; i < MCHUNK; ++i) {
        const int lj = ch * MCHUNK + i;      // local record index, ascending in i
        const int base = (lj >> 3) * 49 + (lj & 7) * 6;
        const float4 r0 = sT[base + 0];
        const float4 r1 = sT[base + 1];
        const float4 r2 = sT[base + 2];
        const float4 r3 = sT[base + 3];
        const float4 r4 = sT[base + 4];
        const float4 r5 = sT[base + 5];
        const float ax = r0.x, ay = r0.y, az = r0.z, nna = r0.w;
        const float abx = r1.x, aby = r1.y, abz = r1.z, rab2 = r1.w;
        const float acx = r2.x, acy = r2.y, acz = r2.z, rac2 = r2.w;
        const float cbx = r3.x, cby = r3.y, cbz = r3.z, rcb2 = r3.w;
        const float nx = r4.x, ny = r4.y, nz = r4.z, abac = r4.w;
        const float naba = r5.x, naca = r5.y, ab2 = r5.z, ac2 = r5.w;

        const v2 d1 = pfma((v2)abz, Z, pfma((v2)aby, Y, pfma((v2)abx, X, (v2)naba)));
        const v2 d2 = pfma((v2)acz, Z, pfma((v2)acy, Y, pfma((v2)acx, X, (v2)naca)));
        const v2 h  = pfma((v2)nz,  Z, pfma((v2)ny,  Y, pfma((v2)nx,  X, (v2)nna)));
        const v2 d3 = d1 - (v2)ab2;
        const v2 d4 = d2 - (v2)abac;
        const v2 d5 = d1 - (v2)abac;
        const v2 d6 = d2 - (v2)ac2;

        const v2 vc = pfma(d1, d4, -(d3*d2));
        const v2 vb = pfma(d5, d2, -(d1*d6));
        const v2 va = pfma(d3, d6, -(d5*d4));
        const v2 t43 = d4 - d3;

        const v2 v_ab = pclip01(d1 * (v2)rab2);
        const v2 v_ac = pclip01(d2 * (v2)rac2);
        const v2 v_bc = pclip01(t43 * (v2)rcb2);

        const v2 apx = X - (v2)ax, apy = Y - (v2)ay, apz = Z - (v2)az;
        const v2 bpx = apx - (v2)abx, bpy = apy - (v2)aby, bpz = apz - (v2)abz;

        v2 ex = pfma(-v_ab, (v2)abx, apx);
        v2 ey = pfma(-v_ab, (v2)aby, apy);
        v2 ez = pfma(-v_ab, (v2)abz, apz);
        const v2 dAB = pfma(ez, ez, pfma(ey, ey, ex*ex));
        ex = pfma(-v_ac, (v2)acx, apx);
        ey = pfma(-v_ac, (v2)acy, apy);
        ez = pfma(-v_ac, (v2)acz, apz);
        const v2 dAC = pfma(ez, ez, pfma(ey, ey, ex*ex));
        ex = pfma(-v_bc, (v2)cbx, bpx);
        ey = pfma(-v_bc, (v2)cby, bpy);
        ez = pfma(-v_bc, (v2)cbz, bpz);
        const v2 dBC = pfma(ez, ez, pfma(ey, ey, ex*ex));
        const v2 dF = h * h;

        const v2 mv   = pmin(pmin(va, vb), vc);
        const v2 dseg = pmin(pmin(dAB, dAC), dBC);

#pragma unroll
        for (int c = 0; c < NPT; ++c) {
            const float dist2 = (mv[c] >= 0.0f) ? dF[c] : dseg[c];
            // strict < ascending lj: first-occurrence tie-break like np.argmin
            if (dist2 < bestd[c]) { bestd[c] = dist2; bestj[c] = jbase + lj; }
        }
    }

    // ---- in-wave butterfly over the 4 chunks this wave holds ----
#pragma unroll
    for (int np = 0; np < NPT; ++np) {
        for (int off = 16; off <= 32; off <<= 1) {
            const float od = __shfl_xor(bestd[np], off, 64);
            const int   oj = __shfl_xor(bestj[np], off, 64);
            if (od < bestd[np] || (od == bestd[np] && oj < bestj[np])) {
                bestd[np] = od; bestj[np] = oj;
            }
        }
    }
    const int lane = t & 63;
    const int w    = t >> 6;                 // wave [0,8)
    if (lane < PTS) {
#pragma unroll
        for (int np = 0; np < NPT; ++np) {
            sPd[np][w * PTS + lane] = bestd[np];
            sPj[np][w * PTS + lane] = bestj[np];
        }
    }
    __syncthreads();

    if (t < 32) {
        const int np = t >> 4;
        const int p  = t & 15;
        float bd = INFINITY; int bj = 0;
        for (int k = 0; k < 8; ++k) {
            const float dk = sPd[np][k * PTS + p];
            const int   jk = sPj[np][k * PTS + p];
            if (dk < bd || (dk == bd && jk < bj)) { bd = dk; bj = jk; }
        }
        const int gidx = b * NN + pb * 32 + t;   // t == np*16 + p
        wd[half * NPTS_TOT + gidx] = bd;
        wj[half * NPTS_TOT + gidx] = bj;
    }
}

// ---- phase-2 kernel: merge halves, exact recompute, write outputs ----
__global__ __launch_bounds__(256) void tridist_p2(
    const float* __restrict__ xyz1, const float* __restrict__ tri1,
    const float* __restrict__ tri2, const float* __restrict__ tri3,
    const float* __restrict__ wd, const int* __restrict__ wj,
    float* __restrict__ out)
{
    const int gidx = blockIdx.x * 256 + threadIdx.x;   // [0, 16384)
    const float d0 = wd[gidx];
    const float d1 = wd[NPTS_TOT + gidx];
    const int   j0 = wj[gidx];
    const int   j1 = wj[NPTS_TOT + gidx];
    // half0's j are all < half1's j, so strict < gives np.argmin first-occurrence.
    const int bj = (d1 < d0) ? j1 : j0;

    const int b = gidx >> 12;                // 4096 points per batch
    const float* g1 = tri1 + ((size_t)b * MM + bj) * 3;
    const float* g2 = tri2 + ((size_t)b * MM + bj) * 3;
    const float* g3 = tri3 + ((size_t)b * MM + bj) * 3;
    float dist2; int reg;
    exact_pair(xyz1[gidx*3+0], xyz1[gidx*3+1], xyz1[gidx*3+2],
               g1[0], g1[1], g1[2],
               g2[0], g2[1], g2[2],
               g3[0], g3[1], g3[2],
               &dist2, &reg);
    out[gidx]               = dist2;
    out[NPTS_TOT + gidx]    = (float)reg;
    out[2*NPTS_TOT + gidx]  = (float)bj;
}

extern "C" void kernel_launch(void* const* d_in, const int* in_sizes, int n_in,
                              void* d_out, int out_size, void* d_ws, size_t ws_size,
                              hipStream_t stream) {
    const float* xyz1 = (const float*)d_in[0];
    const float* tri1 = (const float*)d_in[1];
    const float* tri2 = (const float*)d_in[2];
    const float* tri3 = (const float*)d_in[3];
    float* out = (float*)d_out;

    float* wd = (float*)d_ws;                        // 2 * 16384 floats
    int*   wj = (int*)((char*)d_ws + 2 * NPTS_TOT * sizeof(float));

    dim3 grid1(BB * (NN / 32) * 2);   // 1024 blocks -> 4 blocks/CU target
    tridist_p1<<<grid1, TPB, 0, stream>>>(xyz1, tri1, tri2, tri3, wd, wj);

    dim3 grid2(NPTS_TOT / 256);       // 64 blocks
    tridist_p2<<<grid2, 256, 0, stream>>>(xyz1, tri1, tri2, tri3, wd, wj, out);
}